// Round 3
// baseline (9691.928 us; speedup 1.0000x reference)
//
#include <hip/hip_runtime.h>
#include <hip/hip_bf16.h>

#define S_LEN 16384
#define N_IN 23
#define CH2 16
#define NCH2 (S_LEN / CH2)     // 1024 chunks
#define RING_D 8               // ring slots per stage
#define LAG 6                  // chunk lag of layer B behind layer A in a pair

#define L2E     1.442695041f
#define TWO_L2E 2.885390082f

typedef _Float16 h2v __attribute__((ext_vector_type(2)));

// ---------------- fast activations ----------------
__device__ __forceinline__ float fexp2(float x) {
#if __has_builtin(__builtin_amdgcn_exp2f)
    return __builtin_amdgcn_exp2f(x);
#else
    return exp2f(x);
#endif
}
__device__ __forceinline__ float ftanh_fast(float x) {
    float e = __expf(-2.f * fabsf(x));                // in (0,1]
    float r = (1.f - e) * __builtin_amdgcn_rcpf(1.f + e);
    return x >= 0.f ? r : -r;
}
__device__ __forceinline__ float rlane(float v, int k) {
    return __uint_as_float(__builtin_amdgcn_readlane(__float_as_uint(v), k));
}
__device__ __forceinline__ h2v rlane_h2(h2v v, int k) {
    int b;
    __builtin_memcpy(&b, &v, 4);
    b = __builtin_amdgcn_readlane(b, k);
    h2v r;
    __builtin_memcpy(&r, &b, 4);
    return r;
}
__device__ __forceinline__ h2v pack_h2(float a, float b) {
    auto p = __builtin_amdgcn_cvt_pkrtz(a, b);
    h2v r;
    __builtin_memcpy(&r, &p, 4);
    return r;
}
// lane 2k <-> 2k+1 swap via DPP quad_perm:[1,0,3,2] (pure VALU, no LDS)
__device__ __forceinline__ float dpp_xor1(float v) {
    int b = __float_as_int(v);
    int r = __builtin_amdgcn_update_dpp(b, b, 0xB1, 0xF, 0xF, false);
    return __int_as_float(r);
}

#if __has_builtin(__builtin_amdgcn_fdot2)
__device__ __forceinline__ float fdot2_hw(h2v w, h2v h, float acc) {
    return __builtin_amdgcn_fdot2(w, h, acc, false);
}
#define FDOT2(w, h, acc) fdot2_hw((w), (h), (acc))
#else
__device__ __forceinline__ float fdot2_sw(h2v w, h2v h, float acc) {
    return acc + (float)w.x * (float)h.x + (float)w.y * (float)h.y;
}
#define FDOT2(w, h, acc) fdot2_sw((w), (h), (acc))
#endif

// ---------------- dtype autodetect ----------------
__global__ void detect_kernel(const void* probe, int nsamp, int* flag)
{
    if (blockIdx.x == 0 && threadIdx.x == 0) {
        const unsigned short* p = (const unsigned short*)probe;
        int isbf16 = 1;
        for (int i = 0; i < nsamp; i++) {
            float v = __uint_as_float(((unsigned int)p[i]) << 16);
            if (!(fabsf(v) < 1e4f)) { isbf16 = 0; break; }
        }
        *flag = isbf16;
    }
}

// ---------------- ingest ----------------
struct IngestArgs {
    const void* src[N_IN];
    float*      dst[N_IN];
    int         n[N_IN];
};

__global__ void ingest_kernel(IngestArgs args, const int* __restrict__ flag)
{
    const int isbf16 = *flag;
    const int tid    = blockIdx.x * blockDim.x + threadIdx.x;
    const int stride = gridDim.x * blockDim.x;
    for (int i = 0; i < N_IN; i++) {
        const int n = args.n[i];
        float* dst  = args.dst[i];
        if (isbf16) {
            const unsigned short* s = (const unsigned short*)args.src[i];
            for (int j = tid; j < n; j += stride)
                dst[j] = __uint_as_float(((unsigned int)s[j]) << 16);
        } else {
            const float* s = (const float*)args.src[i];
            for (int j = tid; j < n; j += stride)
                dst[j] = s[j];
        }
    }
}

__global__ void init_kernel(int* prog)
{
    int t = threadIdx.x;
    if (t < 1024) prog[t] = 0;
}

// ---------------- fc1 + fc2 ----------------
__global__ void fc12_kernel(const float* __restrict__ x,
                            const float* __restrict__ W1, const float* __restrict__ b1,
                            const float* __restrict__ W2, const float* __restrict__ b2,
                            float* __restrict__ h2out)
{
    int s = blockIdx.x * blockDim.x + threadIdx.x;
    if (s >= S_LEN) return;
    float xin[6];
#pragma unroll
    for (int k = 0; k < 6; k++) xin[k] = x[s * 6 + k];
    float h1[20];
#pragma unroll
    for (int j = 0; j < 20; j++) {
        float a = b1[j];
#pragma unroll
        for (int k = 0; k < 6; k++) a += W1[j * 6 + k] * xin[k];
        h1[j] = a > 0.f ? a : 0.f;
    }
#pragma unroll
    for (int j = 0; j < 20; j++) {
        float a = b2[j];
#pragma unroll
        for (int k = 0; k < 20; k++) a += W2[j * 20 + k] * h1[k];
        h2out[s * 20 + j] = a > 0.f ? a : 0.f;
    }
}

// =========== producer ====
template <int DIN, int NG, bool TRANS>
__device__ void producer_block(const float* __restrict__ in,    // [S, DIN]
                               const float* __restrict__ Wih,   // [NG, DIN]
                               const float* __restrict__ bih,
                               const float* __restrict__ bhh,
                               float* __restrict__ ring,        // [RING_D][CH2*NG]
                               int* my_prog, int* in_prog, int* cons_prog,
                               float* smem)
{
    constexpr int GR  = NG / 3;                 // row groups
    constexpr int GS  = 256 / GR;               // sl groups
    constexpr int SLT = (CH2 + GS - 1) / GS;    // sl per thread (>=1)

    const int t  = threadIdx.x;
    const int rg = t % GR;
    const int sg = t / GR;

    float* in_sh = smem;             // CH2*DIN
    float* xw_sh = smem + CH2 * DIN; // CH2*NG

    float w[3][DIN];
    float bs[3];
    int cellr[3], partr[3];
#pragma unroll
    for (int r = 0; r < 3; r++) {
        const int row = rg * 3 + r;
        const float fac = TRANS ? ((row / 48) == 2 ? TWO_L2E : L2E) : 1.f;
#pragma unroll
        for (int k = 0; k < DIN; k++) w[r][k] = Wih[row * DIN + k] * fac;
        bs[r] = (bih[row] + bhh[row]) * fac;
        cellr[r] = row % 48;
        partr[r] = row / 48;
    }

    const float4* x4 = (const float4*)in_sh;

    for (int c = 0; c < NCH2; c++) {
        if (t == 0) {
            if (in_prog) {
                while (__hip_atomic_load(in_prog, __ATOMIC_ACQUIRE, __HIP_MEMORY_SCOPE_AGENT) < c + 1)
                    __builtin_amdgcn_s_sleep(1);
            }
            if (c >= RING_D) {
                while (__hip_atomic_load(cons_prog, __ATOMIC_ACQUIRE, __HIP_MEMORY_SCOPE_AGENT) < c - RING_D + 1)
                    __builtin_amdgcn_s_sleep(1);
            }
        }
        __syncthreads();
        {   // input chunk -> LDS
            const float4* gsrc = (const float4*)(in + (size_t)c * CH2 * DIN);
            float4* ldst = (float4*)in_sh;
            for (int i = t; i < CH2 * DIN / 4; i += 256) ldst[i] = gsrc[i];
        }
        __syncthreads();

#pragma unroll
        for (int i = 0; i < SLT; i++) {
            const int sl = sg * SLT + i;
            if (sl < CH2) {
                float a0 = bs[0], a1 = bs[1], a2 = bs[2];
#pragma unroll
                for (int k = 0; k < DIN / 4; k++) {
                    float4 xv = x4[sl * (DIN / 4) + k];
                    a0 += w[0][4 * k + 0] * xv.x; a0 += w[0][4 * k + 1] * xv.y;
                    a0 += w[0][4 * k + 2] * xv.z; a0 += w[0][4 * k + 3] * xv.w;
                    a1 += w[1][4 * k + 0] * xv.x; a1 += w[1][4 * k + 1] * xv.y;
                    a1 += w[1][4 * k + 2] * xv.z; a1 += w[1][4 * k + 3] * xv.w;
                    a2 += w[2][4 * k + 0] * xv.x; a2 += w[2][4 * k + 1] * xv.y;
                    a2 += w[2][4 * k + 2] * xv.z; a2 += w[2][4 * k + 3] * xv.w;
                }
                if (TRANS) {
                    xw_sh[(sl * 48 + cellr[0]) * 4 + partr[0]] = a0;
                    xw_sh[(sl * 48 + cellr[1]) * 4 + partr[1]] = a1;
                    xw_sh[(sl * 48 + cellr[2]) * 4 + partr[2]] = a2;
                } else {
                    xw_sh[sl * NG + rg * 3 + 0] = a0;
                    xw_sh[sl * NG + rg * 3 + 1] = a1;
                    xw_sh[sl * NG + rg * 3 + 2] = a2;
                }
            }
        }
        __syncthreads();
        {   // xw chunk -> ring slot
            const float4* lsrc = (const float4*)xw_sh;
            float4* gdst = (float4*)(ring + (size_t)(c % RING_D) * CH2 * NG);
            for (int i = t; i < CH2 * NG / 4; i += 256) gdst[i] = lsrc[i];
        }
        __syncthreads();
        if (t == 0)
            __hip_atomic_store(my_prog, c + 1, __ATOMIC_RELEASE, __HIP_MEMORY_SCOPE_AGENT);
    }
}

// =========== LSTM step (one cell-step of one layer, lane j owns cell j) ======
__device__ __forceinline__ void lstm_step(
    const h2v (&wI)[24], const h2v (&wF)[24], const h2v (&wG)[24], const h2v (&wO)[24],
    const float4* __restrict__ xfl,   // lane-adjusted: parity base + j
    int sl, float4& xw4, float& hvec, float& ccell,
    float*& hst, int hstr)
{
    float4 nxt = xfl[(sl + 1) * 48];   // prefetch; sl=CH2-1 over-reads (discarded)
    float hn = dpp_xor1(hvec);
    h2v hp = pack_h2(hvec, hn);
    float aI = xw4.x, aF = xw4.y, aG = xw4.z, aO = xw4.w;
#pragma unroll
    for (int kp = 0; kp < 24; kp++) {
        h2v hb = rlane_h2(hp, 2 * kp);
        aI = FDOT2(wI[kp], hb, aI);
        aF = FDOT2(wF[kp], hb, aF);
        aG = FDOT2(wG[kp], hb, aG);
        aO = FDOT2(wO[kp], hb, aO);
    }
    // pre-activations pre-scaled by log2e (g by 2*log2e)
    float eI = fexp2(-aI);
    float eF = fexp2(-aF);
    float eG = fexp2(-fabsf(aG));          // (0,1], never overflows
    float eO = fexp2(-aO);
    float fv = __builtin_amdgcn_rcpf(1.f + eF);               // eF=inf -> 0, safe
    float ig = (1.f - eG) * __builtin_amdgcn_rcpf((1.f + eI) * (1.f + eG));
    ig = __int_as_float(__float_as_int(ig) ^ (__float_as_int(aG) & 0x80000000));
    ccell = fmaf(fv, ccell, ig);
    float eC = fexp2(-TWO_L2E * fabsf(ccell));
    float r  = (1.f - eC) * __builtin_amdgcn_rcpf((1.f + eO) * (1.f + eC));
    float h  = __int_as_float(__float_as_int(r) ^ (__float_as_int(ccell) & 0x80000000));
    hvec = h;
    *hst = h; hst += hstr;                 // lanes 48-63: stride-0 dump (no exec games)
    xw4 = nxt;
}

__device__ __forceinline__ void lstm_load_w(const float* __restrict__ Whh, int j,
    h2v (&wI)[24], h2v (&wF)[24], h2v (&wG)[24], h2v (&wO)[24])
{
#pragma unroll
    for (int k = 0; k < 24; k++) {
        wI[k] = pack_h2(Whh[j * 48 + 2 * k] * L2E,            Whh[j * 48 + 2 * k + 1] * L2E);
        wF[k] = pack_h2(Whh[(48 + j) * 48 + 2 * k] * L2E,     Whh[(48 + j) * 48 + 2 * k + 1] * L2E);
        wG[k] = pack_h2(Whh[(96 + j) * 48 + 2 * k] * TWO_L2E, Whh[(96 + j) * 48 + 2 * k + 1] * TWO_L2E);
        wO[k] = pack_h2(Whh[(144 + j) * 48 + 2 * k] * L2E,    Whh[(144 + j) * 48 + 2 * k + 1] * L2E);
    }
}

// =========== RNN step =========================================================
__device__ __forceinline__ void rnn_step(
    const float (&whh)[24], const float* __restrict__ xwc,
    int sl, float& xwv, float& hvec, float*& hst, int hstr, int tB)
{
    float nxtx = xwc[(sl + 1) * 24 + tB];   // over-read at chunk end: discarded
    float a0 = xwv, a1 = 0.f, a2 = 0.f, a3 = 0.f;
#pragma unroll
    for (int k = 0; k < 24; k += 4) {
        a0 += rlane(hvec, k + 0) * whh[k + 0];
        a1 += rlane(hvec, k + 1) * whh[k + 1];
        a2 += rlane(hvec, k + 2) * whh[k + 2];
        a3 += rlane(hvec, k + 3) * whh[k + 3];
    }
    float h = ftanh_fast((a0 + a1) + (a2 + a3));
    hvec = h;
    *hst = h; hst += hstr;
    xwv = nxtx;
}

// =========== paired LSTM+LSTM scan: two layers interleaved on one wave ========
// Layer B lags layer A by LAG chunks; each combined step issues both layers'
// step bodies back-to-back so each stream's dependency stalls are filled by
// the other stream's independent instructions.
__device__ void lstm_scan_pair(
    const float* __restrict__ WhhA, const float* __restrict__ ringA,
    float* __restrict__ hseqA, int* spA, int* ppA,
    const float* __restrict__ WhhB, const float* __restrict__ ringB,
    float* __restrict__ hseqB, int* spB, int* ppB,
    float* __restrict__ smem)
{
    const int t = threadIdx.x;
    const int j = (t < 48) ? t : 47;
    // floats: xwA[0:6144) xwB[6144:12288) hhA[12288:13824) hhB[13824:15360) dump[15360:15424)
    float* xwA  = smem;
    float* xwB  = smem + 6144;
    float* hhA  = smem + 12288;
    float* hhB  = smem + 13824;
    float* dump = smem + 15360;

    h2v wIA[24], wFA[24], wGA[24], wOA[24];
    h2v wIB[24], wFB[24], wGB[24], wOB[24];
    if (t < 64) {
        lstm_load_w(WhhA, j, wIA, wFA, wGA, wOA);
        lstm_load_w(WhhB, j, wIB, wFB, wGB, wOB);
    }
    float hA = 0.f, cAc = 0.f, hB = 0.f, cBc = 0.f;
    const int hstr = (t < 48) ? 48 : 0;

    if (t >= 128) {   // prologue: stage A slot 0
        while (__hip_atomic_load(ppA, __ATOMIC_ACQUIRE, __HIP_MEMORY_SCOPE_AGENT) < 1)
            __builtin_amdgcn_s_sleep(8);
        const float4* g = (const float4*)ringA;
        float4* d = (float4*)xwA;
        for (int i = t - 128; i < CH2 * 48; i += 128) d[i] = g[i];
    }
    __syncthreads();

    for (int cc = 0; cc < NCH2 + LAG; cc++) {
        const int ca = cc, cb = cc - LAG;
        const bool Aact = ca < NCH2;
        const bool Bact = cb >= 0;
        if (t < 64) {
            const float4* xfA = (const float4*)(xwA + (ca & 1) * (CH2 * 192)) + j;
            const float4* xfB = (const float4*)(xwB + (cb & 1) * (CH2 * 192)) + j;
            float* hsA = (t < 48) ? (hhA + (ca & 1) * (CH2 * 48) + t) : (dump + (t - 48));
            float* hsB = (t < 48) ? (hhB + (cb & 1) * (CH2 * 48) + t) : (dump + (t - 48));
            float4 xwa, xwb;
            if (Aact) xwa = xfA[0];
            if (Bact) xwb = xfB[0];
            if (Aact && Bact) {
                for (int sl = 0; sl < CH2; sl++) {
                    lstm_step(wIA, wFA, wGA, wOA, xfA, sl, xwa, hA, cAc, hsA, hstr);
                    lstm_step(wIB, wFB, wGB, wOB, xfB, sl, xwb, hB, cBc, hsB, hstr);
                }
            } else if (Aact) {
                for (int sl = 0; sl < CH2; sl++)
                    lstm_step(wIA, wFA, wGA, wOA, xfA, sl, xwa, hA, cAc, hsA, hstr);
            } else if (Bact) {
                for (int sl = 0; sl < CH2; sl++)
                    lstm_step(wIB, wFB, wGB, wOB, xfB, sl, xwb, hB, cBc, hsB, hstr);
            }
        } else if (t < 128) {
            if (ca >= 1 && ca <= NCH2) {
                const float4* s4 = (const float4*)(hhA + ((ca - 1) & 1) * (CH2 * 48));
                float4* d4 = (float4*)(hseqA + (size_t)(ca - 1) * CH2 * 48);
                for (int i = t - 64; i < CH2 * 12; i += 64) d4[i] = s4[i];
            }
            if (cb >= 1) {
                const float4* s4 = (const float4*)(hhB + ((cb - 1) & 1) * (CH2 * 48));
                float4* d4 = (float4*)(hseqB + (size_t)(cb - 1) * CH2 * 48);
                for (int i = t - 64; i < CH2 * 12; i += 64) d4[i] = s4[i];
            }
            if (t == 64) {   // wave-level vmcnt drain covers all lanes' stores
                if (ca >= 1 && ca <= NCH2)
                    __hip_atomic_store(spA, ca, __ATOMIC_RELEASE, __HIP_MEMORY_SCOPE_AGENT);
                if (cb >= 1)
                    __hip_atomic_store(spB, cb, __ATOMIC_RELEASE, __HIP_MEMORY_SCOPE_AGENT);
            }
        } else {
            if (ca + 1 < NCH2) {
                while (__hip_atomic_load(ppA, __ATOMIC_ACQUIRE, __HIP_MEMORY_SCOPE_AGENT) < ca + 2)
                    __builtin_amdgcn_s_sleep(8);
                const float4* g = (const float4*)(ringA + (size_t)((ca + 1) % RING_D) * CH2 * 192);
                float4* d = (float4*)(xwA + ((ca + 1) & 1) * (CH2 * 192));
                for (int i = t - 128; i < CH2 * 48; i += 128) d[i] = g[i];
            }
            if (cb + 1 >= 0 && cb + 1 < NCH2) {
                while (__hip_atomic_load(ppB, __ATOMIC_ACQUIRE, __HIP_MEMORY_SCOPE_AGENT) < cb + 2)
                    __builtin_amdgcn_s_sleep(8);
                const float4* g = (const float4*)(ringB + (size_t)((cb + 1) % RING_D) * CH2 * 192);
                float4* d = (float4*)(xwB + ((cb + 1) & 1) * (CH2 * 192));
                for (int i = t - 128; i < CH2 * 48; i += 128) d[i] = g[i];
            }
        }
        __syncthreads();
    }
    // epilogue: B's final chunk
    if (t >= 64 && t < 128) {
        const float4* s4 = (const float4*)(hhB + ((NCH2 - 1) & 1) * (CH2 * 48));
        float4* d4 = (float4*)(hseqB + (size_t)(NCH2 - 1) * CH2 * 48);
        for (int i = t - 64; i < CH2 * 12; i += 64) d4[i] = s4[i];
        if (t == 64)
            __hip_atomic_store(spB, NCH2, __ATOMIC_RELEASE, __HIP_MEMORY_SCOPE_AGENT);
    }
}

// =========== paired LSTM+RNN scan (layer A = LSTM, layer B = tanh-RNN) ========
__device__ void lstm_rnn_pair(
    const float* __restrict__ WhhA, const float* __restrict__ ringA,
    float* __restrict__ hseqA, int* spA, int* ppA,
    const float* __restrict__ WhhB, const float* __restrict__ ringB,
    float* __restrict__ hseqB, int* spB, int* ppB,
    float* __restrict__ smem)
{
    const int t = threadIdx.x;
    const int j  = (t < 48) ? t : 47;
    const int tB = (t < 24) ? t : 23;
    // floats: xwA[0:6144) hhA[6144:7680) xwB[7680:8448) hhB[8448:9216) dump[9216:9280)
    float* xwA  = smem;
    float* hhA  = smem + 6144;
    float* xwB  = smem + 7680;
    float* hhB  = smem + 8448;
    float* dump = smem + 9216;

    h2v wIA[24], wFA[24], wGA[24], wOA[24];
    float whhB[24];
    if (t < 64) lstm_load_w(WhhA, j, wIA, wFA, wGA, wOA);
#pragma unroll
    for (int k = 0; k < 24; k++) whhB[k] = WhhB[tB * 24 + k];
    float hA = 0.f, cAc = 0.f, hB = 0.f;
    const int hstrA = (t < 48) ? 48 : 0;
    const int hstrB = (t < 24) ? 24 : 0;

    if (t >= 128) {   // prologue: stage A slot 0
        while (__hip_atomic_load(ppA, __ATOMIC_ACQUIRE, __HIP_MEMORY_SCOPE_AGENT) < 1)
            __builtin_amdgcn_s_sleep(8);
        const float4* g = (const float4*)ringA;
        float4* d = (float4*)xwA;
        for (int i = t - 128; i < CH2 * 48; i += 128) d[i] = g[i];
    }
    __syncthreads();

    for (int cc = 0; cc < NCH2 + LAG; cc++) {
        const int ca = cc, cb = cc - LAG;
        const bool Aact = ca < NCH2;
        const bool Bact = cb >= 0;
        if (t < 64) {
            const float4* xfA = (const float4*)(xwA + (ca & 1) * (CH2 * 192)) + j;
            const float* xwcB = xwB + (cb & 1) * (CH2 * 24);
            float* hsA = (t < 48) ? (hhA + (ca & 1) * (CH2 * 48) + t) : (dump + (t - 48));
            float* hsB = (t < 24) ? (hhB + (cb & 1) * (CH2 * 24) + t) : (dump + (t - 24));
            float4 xwa; float xwb = 0.f;
            if (Aact) xwa = xfA[0];
            if (Bact) xwb = xwcB[tB];
            if (Aact && Bact) {
                for (int sl = 0; sl < CH2; sl++) {
                    lstm_step(wIA, wFA, wGA, wOA, xfA, sl, xwa, hA, cAc, hsA, hstrA);
                    rnn_step(whhB, xwcB, sl, xwb, hB, hsB, hstrB, tB);
                }
            } else if (Aact) {
                for (int sl = 0; sl < CH2; sl++)
                    lstm_step(wIA, wFA, wGA, wOA, xfA, sl, xwa, hA, cAc, hsA, hstrA);
            } else if (Bact) {
                for (int sl = 0; sl < CH2; sl++)
                    rnn_step(whhB, xwcB, sl, xwb, hB, hsB, hstrB, tB);
            }
        } else if (t < 128) {
            if (ca >= 1 && ca <= NCH2) {
                const float4* s4 = (const float4*)(hhA + ((ca - 1) & 1) * (CH2 * 48));
                float4* d4 = (float4*)(hseqA + (size_t)(ca - 1) * CH2 * 48);
                for (int i = t - 64; i < CH2 * 12; i += 64) d4[i] = s4[i];
            }
            if (cb >= 1) {
                const float4* s4 = (const float4*)(hhB + ((cb - 1) & 1) * (CH2 * 24));
                float4* d4 = (float4*)(hseqB + (size_t)(cb - 1) * CH2 * 24);
                for (int i = t - 64; i < CH2 * 6; i += 64) d4[i] = s4[i];
            }
            if (t == 64) {
                if (ca >= 1 && ca <= NCH2)
                    __hip_atomic_store(spA, ca, __ATOMIC_RELEASE, __HIP_MEMORY_SCOPE_AGENT);
                if (cb >= 1)
                    __hip_atomic_store(spB, cb, __ATOMIC_RELEASE, __HIP_MEMORY_SCOPE_AGENT);
            }
        } else {
            if (ca + 1 < NCH2) {
                while (__hip_atomic_load(ppA, __ATOMIC_ACQUIRE, __HIP_MEMORY_SCOPE_AGENT) < ca + 2)
                    __builtin_amdgcn_s_sleep(8);
                const float4* g = (const float4*)(ringA + (size_t)((ca + 1) % RING_D) * CH2 * 192);
                float4* d = (float4*)(xwA + ((ca + 1) & 1) * (CH2 * 192));
                for (int i = t - 128; i < CH2 * 48; i += 128) d[i] = g[i];
            }
            if (cb + 1 >= 0 && cb + 1 < NCH2) {
                while (__hip_atomic_load(ppB, __ATOMIC_ACQUIRE, __HIP_MEMORY_SCOPE_AGENT) < cb + 2)
                    __builtin_amdgcn_s_sleep(8);
                const float4* g = (const float4*)(ringB + (size_t)((cb + 1) % RING_D) * CH2 * 24);
                float4* d = (float4*)(xwB + ((cb + 1) & 1) * (CH2 * 24));
                for (int i = t - 128; i < CH2 * 6; i += 128) d[i] = g[i];
            }
        }
        __syncthreads();
    }
    // epilogue: B's final chunk
    if (t >= 64 && t < 128) {
        const float4* s4 = (const float4*)(hhB + ((NCH2 - 1) & 1) * (CH2 * 24));
        float4* d4 = (float4*)(hseqB + (size_t)(NCH2 - 1) * CH2 * 24);
        for (int i = t - 64; i < CH2 * 6; i += 64) d4[i] = s4[i];
        if (t == 64)
            __hip_atomic_store(spB, NCH2, __ATOMIC_RELEASE, __HIP_MEMORY_SCOPE_AGENT);
    }
}

// =========== solo tanh-RNN scan (R1) ==========================================
__device__ void rnn_scan(const float* __restrict__ Whh,      // [24, 24]
                         const float* __restrict__ ring,     // [RING_D][CH2*24]
                         float* __restrict__ hseq,           // [S, 24]
                         int* my_prog, int* prod_prog, float* smem)
{
    const int t = threadIdx.x;
    float* xw_buf = smem;                 // 2 * CH2*24
    float* hh_buf = smem + 1536;

    float whh[24];
    if (t < 24) {
#pragma unroll
        for (int k = 0; k < 24; k++) whh[k] = Whh[t * 24 + k];
    }
    float hvec = 0.f;

    if (t >= 128) {
        while (__hip_atomic_load(prod_prog, __ATOMIC_ACQUIRE, __HIP_MEMORY_SCOPE_AGENT) < 1)
            __builtin_amdgcn_s_sleep(8);
        const float4* g = (const float4*)ring;
        float4* d = (float4*)xw_buf;
        for (int i = t - 128; i < CH2 * 6; i += 128) d[i] = g[i];
    }
    __syncthreads();

    for (int c = 0; c < NCH2; c++) {
        if (t < 64) {
            const float* xwc = xw_buf + (c & 1) * (CH2 * 24);
            float* hh = hh_buf + (c & 1) * (CH2 * 24);
            float xwv = (t < 24) ? xwc[t] : 0.f;
            for (int sl = 0; sl < CH2; sl++) {
                float nxtx = (t < 24) ? xwc[((sl + 1 < CH2) ? sl + 1 : sl) * 24 + t] : 0.f;
                float a0 = xwv, a1 = 0.f, a2 = 0.f, a3 = 0.f;
#pragma unroll
                for (int k = 0; k < 24; k += 4) {
                    a0 += rlane(hvec, k + 0) * whh[k + 0];
                    a1 += rlane(hvec, k + 1) * whh[k + 1];
                    a2 += rlane(hvec, k + 2) * whh[k + 2];
                    a3 += rlane(hvec, k + 3) * whh[k + 3];
                }
                float h = ftanh_fast((a0 + a1) + (a2 + a3));
                if (t < 24) {
                    hvec = h;
                    hh[sl * 24 + t] = h;
                }
                xwv = nxtx;
            }
        } else if (t < 128) {
            if (c >= 1) {
                const float4* s4 = (const float4*)(hh_buf + ((c - 1) & 1) * (CH2 * 24));
                float4* d4 = (float4*)(hseq + (size_t)(c - 1) * CH2 * 24);
                for (int i = t - 64; i < CH2 * 6; i += 64) d4[i] = s4[i];
                if (t == 64)
                    __hip_atomic_store(my_prog, c, __ATOMIC_RELEASE, __HIP_MEMORY_SCOPE_AGENT);
            }
        } else {
            if (c + 1 < NCH2) {
                while (__hip_atomic_load(prod_prog, __ATOMIC_ACQUIRE, __HIP_MEMORY_SCOPE_AGENT) < c + 2)
                    __builtin_amdgcn_s_sleep(8);
                const float4* g = (const float4*)(ring + (size_t)((c + 1) % RING_D) * CH2 * 24);
                float4* d = (float4*)(xw_buf + ((c + 1) & 1) * (CH2 * 24));
                for (int i = t - 128; i < CH2 * 6; i += 128) d[i] = g[i];
            }
        }
        __syncthreads();
    }
    if (t >= 64 && t < 128) {
        const float4* s4 = (const float4*)(hh_buf + ((NCH2 - 1) & 1) * (CH2 * 24));
        float4* d4 = (float4*)(hseq + (size_t)(NCH2 - 1) * CH2 * 24);
        for (int i = t - 64; i < CH2 * 6; i += 64) d4[i] = s4[i];
        if (t == 64)
            __hip_atomic_store(my_prog, NCH2, __ATOMIC_RELEASE, __HIP_MEMORY_SCOPE_AGENT);
    }
}

// ---------------- the 11-block pipeline megakernel ----------------
struct PipeArgs {
    const float* h2;
    const float* l0_Wih; const float* l0_Whh; const float* l0_bih; const float* l0_bhh;
    const float* lr_Wih; const float* lr_Whh; const float* lr_bih; const float* lr_bhh;
    const float* r0_Wih; const float* r0_Whh; const float* r0_bih; const float* r0_bhh;
    const float* r1_Wih; const float* r1_Whh; const float* r1_bih; const float* r1_bhh;
    float* seq0; float* seq1; float* seq2; float* seq3; float* seq4;
    float* rnnA; float* rnnB;
    float* ring[7];
    int* prog;        // scan l: prog[l*64]; producer l: prog[(8+l)*64]
};

__global__ void __launch_bounds__(256, 1) pipeline_kernel(PipeArgs a)
{
    __shared__ __align__(16) float smem[15424];   // 61696 B (LSTM-pair worst case)
    const int b = blockIdx.x;
    const float* seqin[7] = {a.h2, a.seq0, a.seq1, a.seq2, a.seq3, a.seq4, a.rnnA};
    int* sp[7]; int* pp[7];
    for (int l = 0; l < 7; l++) { sp[l] = a.prog + l * 64; pp[l] = a.prog + (8 + l) * 64; }

    if (b < 7) {
        // ---- producers (unchanged protocol) ----
        const int l = b;
        int* inp = (l == 0) ? nullptr : sp[l - 1];
        if (l == 0) {
            producer_block<20, 192, true>(a.h2, a.l0_Wih, a.l0_bih, a.l0_bhh,
                                          a.ring[0], pp[0], inp, sp[0], smem);
        } else if (l <= 4) {
            producer_block<48, 192, true>(seqin[l],
                                          a.lr_Wih + (size_t)(l - 1) * 192 * 48,
                                          a.lr_bih + (size_t)(l - 1) * 192,
                                          a.lr_bhh + (size_t)(l - 1) * 192,
                                          a.ring[l], pp[l], inp, sp[l], smem);
        } else if (l == 5) {
            producer_block<48, 24, false>(a.seq4, a.r0_Wih, a.r0_bih, a.r0_bhh,
                                          a.ring[5], pp[5], inp, sp[5], smem);
        } else {
            producer_block<24, 24, false>(a.rnnA, a.r1_Wih, a.r1_bih, a.r1_bhh,
                                          a.ring[6], pp[6], inp, sp[6], smem);
        }
    } else if (b == 7) {
        lstm_scan_pair(a.l0_Whh, a.ring[0], a.seq0, sp[0], pp[0],
                       a.lr_Whh,  a.ring[1], a.seq1, sp[1], pp[1], smem);
    } else if (b == 8) {
        lstm_scan_pair(a.lr_Whh + (size_t)1 * 192 * 48, a.ring[2], a.seq2, sp[2], pp[2],
                       a.lr_Whh + (size_t)2 * 192 * 48, a.ring[3], a.seq3, sp[3], pp[3], smem);
    } else if (b == 9) {
        lstm_rnn_pair(a.lr_Whh + (size_t)3 * 192 * 48, a.ring[4], a.seq4, sp[4], pp[4],
                      a.r0_Whh, a.ring[5], a.rnnA, sp[5], pp[5], smem);
    } else {
        rnn_scan(a.r1_Whh, a.ring[6], a.rnnB, sp[6], pp[6], smem);
    }
}

// ---------------- epilogue: relu + fc4 ----------------
__global__ void out_kernel(const float* __restrict__ hin,
                           const float* __restrict__ W,  // [2, 24]
                           const float* __restrict__ b,  // [2]
                           void* __restrict__ out,
                           const int* __restrict__ flag)
{
    int s = blockIdx.x * blockDim.x + threadIdx.x;
    if (s >= S_LEN) return;
    const int isbf16 = *flag;
    float h[24];
#pragma unroll
    for (int k = 0; k < 24; k++) {
        float v = hin[s * 24 + k];
        h[k] = v > 0.f ? v : 0.f;
    }
#pragma unroll
    for (int j = 0; j < 2; j++) {
        float a = b[j];
#pragma unroll
        for (int k = 0; k < 24; k++) a += W[j * 24 + k] * h[k];
        if (isbf16) ((__hip_bfloat16*)out)[s * 2 + j] = __float2bfloat16(a);
        else        ((float*)out)[s * 2 + j] = a;
    }
}

extern "C" void kernel_launch(void* const* d_in, const int* in_sizes, int n_in,
                              void* d_out, int out_size, void* d_ws, size_t ws_size,
                              hipStream_t stream)
{
    int*   ip    = (int*)d_ws;        // [0]: dtype flag; [256..1280): progress slots
    int*   flag  = ip;
    int*   prog  = ip + 256;
    float* ws    = (float*)d_ws;
    float* conv0 = ws + 4096;

    IngestArgs ia;
    float* conv[N_IN];
    {
        float* p = conv0;
        for (int i = 0; i < N_IN; i++) {
            conv[i] = p;
            ia.src[i] = d_in[i];
            ia.dst[i] = p;
            ia.n[i]   = in_sizes[i];
            p += in_sizes[i];
        }
    }
    float* h2   = conv0 + 191000;       // [S,20]  327,680
    float* seq0 = h2 + 327680;          // 5 x [S,48]
    float* seq1 = seq0 + 786432;
    float* seq2 = seq1 + 786432;
    float* seq3 = seq2 + 786432;
    float* seq4 = seq3 + 786432;
    float* rnnA = seq4 + 786432;        // [S,24]
    float* rnnB = rnnA + 393216;        // [S,24]
    float* rbase = rnnB + 393216;       // rings
    float* ring[7];
    {
        float* p = rbase;
        for (int l = 0; l < 5; l++) { ring[l] = p; p += RING_D * CH2 * 192; }
        for (int l = 5; l < 7; l++) { ring[l] = p; p += RING_D * CH2 * 24;  }
    }

    const int TPB = 256;
    const int NB  = S_LEN / TPB;  // 64

    detect_kernel<<<1, 64, 0, stream>>>(d_in[1], in_sizes[1], flag);
    ingest_kernel<<<128, 256, 0, stream>>>(ia, flag);
    init_kernel<<<1, 1024, 0, stream>>>(prog);

    fc12_kernel<<<NB, TPB, 0, stream>>>(conv[0], conv[1], conv[2], conv[3], conv[4], h2);

    PipeArgs pa;
    pa.h2 = h2;
    pa.l0_Wih = conv[5];  pa.l0_Whh = conv[6];  pa.l0_bih = conv[7];  pa.l0_bhh = conv[8];
    pa.lr_Wih = conv[9];  pa.lr_Whh = conv[10]; pa.lr_bih = conv[11]; pa.lr_bhh = conv[12];
    pa.r0_Wih = conv[13]; pa.r0_Whh = conv[14]; pa.r0_bih = conv[15]; pa.r0_bhh = conv[16];
    pa.r1_Wih = conv[17]; pa.r1_Whh = conv[18]; pa.r1_bih = conv[19]; pa.r1_bhh = conv[20];
    pa.seq0 = seq0; pa.seq1 = seq1; pa.seq2 = seq2; pa.seq3 = seq3; pa.seq4 = seq4;
    pa.rnnA = rnnA; pa.rnnB = rnnB;
    for (int l = 0; l < 7; l++) pa.ring[l] = ring[l];
    pa.prog = prog;

    pipeline_kernel<<<11, 256, 0, stream>>>(pa);

    out_kernel<<<NB, TPB, 0, stream>>>(rnnB, conv[21], conv[22], d_out, flag);
}